// Round 1
// baseline (138.760 us; speedup 1.0000x reference)
//
#include <hip/hip_runtime.h>

// Problem: out[b,c,h,w] = clip(low[b,c,h,w]*cc[b,c], 1e-8, 1) ^ (mask==0 ? g1[b,c] : g2[b,c])
// B=16, C=3, H=W=512.  H*W = 2^18, total = 12,582,912 elems (divisible by 4).
// Memory-bound streaming kernel: 12 B/elem -> ~151 MB -> ~24 us at 6.3 TB/s.

#define HW_SHIFT 18            // log2(512*512)
#define N_TOTAL  12582912     // 16*3*512*512
#define N_VEC    (N_TOTAL / 4)

__global__ __launch_bounds__(256) void gamma_blend_kernel(
    const float* __restrict__ low,
    const float* __restrict__ g1,
    const float* __restrict__ g2,
    const float* __restrict__ cc,
    const int*   __restrict__ mask,
    float*       __restrict__ out)
{
    const int tid = blockIdx.x * blockDim.x + threadIdx.x;
    if (tid >= N_VEC) return;

    // 4 consecutive elements per thread; all in the same (b,c) plane since
    // the plane size (2^18) is a multiple of 4.
    const int bc = (tid * 4) >> HW_SHIFT;   // which (b,c) plane

    const float c_s  = cc[bc];
    const float e1   = g1[bc];
    const float e2   = g2[bc];

    const float4 lv = reinterpret_cast<const float4*>(low)[tid];
    const int4   mv = reinterpret_cast<const int4*>(mask)[tid];

    float4 ov;
    {
        float x = fminf(fmaxf(lv.x * c_s, 1e-8f), 1.0f);
        float g = (mv.x == 0) ? e1 : e2;
        ov.x = __builtin_amdgcn_exp2f(g * __builtin_amdgcn_logf(x)); // v_log_f32 is log2
    }
    {
        float x = fminf(fmaxf(lv.y * c_s, 1e-8f), 1.0f);
        float g = (mv.y == 0) ? e1 : e2;
        ov.y = __builtin_amdgcn_exp2f(g * __builtin_amdgcn_logf(x));
    }
    {
        float x = fminf(fmaxf(lv.z * c_s, 1e-8f), 1.0f);
        float g = (mv.z == 0) ? e1 : e2;
        ov.z = __builtin_amdgcn_exp2f(g * __builtin_amdgcn_logf(x));
    }
    {
        float x = fminf(fmaxf(lv.w * c_s, 1e-8f), 1.0f);
        float g = (mv.w == 0) ? e1 : e2;
        ov.w = __builtin_amdgcn_exp2f(g * __builtin_amdgcn_logf(x));
    }

    reinterpret_cast<float4*>(out)[tid] = ov;
}

extern "C" void kernel_launch(void* const* d_in, const int* in_sizes, int n_in,
                              void* d_out, int out_size, void* d_ws, size_t ws_size,
                              hipStream_t stream) {
    // setup_inputs order: low_img, g1, g2, c, I_Mask
    const float* low  = (const float*)d_in[0];
    const float* g1   = (const float*)d_in[1];
    const float* g2   = (const float*)d_in[2];
    const float* cc   = (const float*)d_in[3];
    const int*   mask = (const int*)d_in[4];
    float* out = (float*)d_out;

    const int threads = 256;
    const int blocks  = (N_VEC + threads - 1) / threads;   // 12288, exact fit
    gamma_blend_kernel<<<blocks, threads, 0, stream>>>(low, g1, g2, cc, mask, out);
}